// Round 8
// baseline (1395.546 us; speedup 1.0000x reference)
//
#include <hip/hip_runtime.h>

#define HID 256
#define VOC 50257
#define NTOK 4096
#define NCT 197                   // ceil(VOC / 256)
#define LN_EPS 1e-3f
#define PROB_ELEMS 205852672      // 4096 * 50257

typedef __attribute__((ext_vector_type(8))) short bf16x8;
typedef __attribute__((ext_vector_type(4))) float f32x4;
typedef __attribute__((ext_vector_type(4), aligned(4))) float f32x4u;  // 4B-aligned vector store

__device__ inline unsigned short f2bf(float f) {
    unsigned int u = __builtin_bit_cast(unsigned int, f);
    unsigned int r = u + 0x7FFFu + ((u >> 16) & 1u);
    return (unsigned short)(r >> 16);
}
__device__ inline float bf2f(unsigned short b) {
    unsigned int u = ((unsigned int)b) << 16;
    return __builtin_bit_cast(float, u);
}

// ---------------------------------------------------------------- conv f32->bf16
__global__ void conv_f32_bf16(const float* __restrict__ src,
                              unsigned short* __restrict__ dst, int n4) {
    int i = blockIdx.x * blockDim.x + threadIdx.x;
    int stride = gridDim.x * blockDim.x;
    for (; i < n4; i += stride) {
        float4 v = reinterpret_cast<const float4*>(src)[i];
        ushort4 o;
        o.x = f2bf(v.x); o.y = f2bf(v.y); o.z = f2bf(v.z); o.w = f2bf(v.w);
        reinterpret_cast<ushort4*>(dst)[i] = o;
    }
}

// ---------------------------------------------------------------- W transpose: W[e][k][h] f32 -> Wt[e*256+h][k] bf16
__global__ __launch_bounds__(256) void wt_transpose(
    const float* __restrict__ Wsh, const float* __restrict__ Wsp,
    unsigned short* __restrict__ Wtbf) {
    __shared__ float t[64][65];
    int gcol0 = blockIdx.x * 64;
    int k0 = blockIdx.y * 64;
    int e = gcol0 >> 8, h0 = gcol0 & 255;
    const float* Wp = (e < 2) ? (Wsh + e * 65536) : (Wsp + (e - 2) * 65536);
    int tid = threadIdx.x;
#pragma unroll
    for (int i = 0; i < 16; ++i) {
        int id = tid + i * 256;
        int k = id >> 6, h = id & 63;
        t[k][h] = Wp[(k0 + k) * 256 + h0 + h];
    }
    __syncthreads();
#pragma unroll
    for (int i = 0; i < 4; ++i) {
        int id = tid + i * 256;
        int h = id >> 4, kq = id & 15;
        ushort4 o;
        o.x = f2bf(t[kq * 4 + 0][h]); o.y = f2bf(t[kq * 4 + 1][h]);
        o.z = f2bf(t[kq * 4 + 2][h]); o.w = f2bf(t[kq * 4 + 3][h]);
        *reinterpret_cast<ushort4*>(Wtbf + (size_t)(gcol0 + h) * 256 + k0 + kq * 4) = o;
    }
}

// ---------------------------------------------------------------- expert GEMM
__global__ __launch_bounds__(256) void expert_gemm(
    const unsigned short* __restrict__ xbf,
    const unsigned short* __restrict__ Wtbf,
    const float* __restrict__ bsh, const float* __restrict__ bsp,
    float* __restrict__ cexp) {
    __shared__ unsigned short sA[64 * 256];
    __shared__ unsigned short sB[128 * 256];
    int bid = blockIdx.x;
    int rt = bid & 63;
    int ct = bid >> 6;
    int row0 = rt * 64, col0 = ct * 128;
    int tid = threadIdx.x;

#pragma unroll
    for (int i = 0; i < 8; ++i) {
        int id = tid + i * 256;
        int r = id >> 5, c = id & 31;
        bf16x8 v = *reinterpret_cast<const bf16x8*>(xbf + (row0 + r) * 256 + c * 8);
        *reinterpret_cast<bf16x8*>(sA + r * 256 + ((c ^ (r & 7)) * 8)) = v;
    }
#pragma unroll
    for (int i = 0; i < 16; ++i) {
        int id = tid + i * 256;
        int j = id >> 5, c = id & 31;
        bf16x8 v = *reinterpret_cast<const bf16x8*>(Wtbf + (size_t)(col0 + j) * 256 + c * 8);
        *reinterpret_cast<bf16x8*>(sB + j * 256 + ((c ^ (j & 7)) * 8)) = v;
    }
    __syncthreads();

    int lane = tid & 63, wave = tid >> 6;
    int wcol = wave * 32;
    int lrow = lane & 15, g = lane >> 4;
    f32x4 zero4 = {0.f, 0.f, 0.f, 0.f};
    f32x4 acc[4][2];
#pragma unroll
    for (int mf = 0; mf < 4; ++mf)
#pragma unroll
        for (int nf = 0; nf < 2; ++nf) acc[mf][nf] = zero4;

#pragma unroll
    for (int ks = 0; ks < 8; ++ks) {
        int kc = ks * 4 + g;
        bf16x8 a[4], b[2];
#pragma unroll
        for (int mf = 0; mf < 4; ++mf) {
            int r = mf * 16 + lrow;
            a[mf] = *reinterpret_cast<const bf16x8*>(sA + r * 256 + ((kc ^ (r & 7)) * 8));
        }
#pragma unroll
        for (int nf = 0; nf < 2; ++nf) {
            int j = wcol + nf * 16 + lrow;
            b[nf] = *reinterpret_cast<const bf16x8*>(sB + j * 256 + ((kc ^ (j & 7)) * 8));
        }
#pragma unroll
        for (int mf = 0; mf < 4; ++mf)
#pragma unroll
            for (int nf = 0; nf < 2; ++nf)
                acc[mf][nf] = __builtin_amdgcn_mfma_f32_16x16x32_bf16(a[mf], b[nf], acc[mf][nf], 0, 0, 0);
    }

#pragma unroll
    for (int nf = 0; nf < 2; ++nf) {
        int col = col0 + wcol + nf * 16 + lrow;
        int e = col >> 8, h = col & 255;
        float bias = (e < 2) ? bsh[e * 256 + h] : bsp[(e - 2) * 256 + h];
#pragma unroll
        for (int mf = 0; mf < 4; ++mf)
#pragma unroll
            for (int r = 0; r < 4; ++r) {
                int row = row0 + mf * 16 + g * 4 + r;
                cexp[(size_t)row * 2560 + col] = acc[mf][nf][r] + bias;
            }
    }
}

// ---------------------------------------------------------------- gates + combine + LN + residual
__global__ __launch_bounds__(256) void combine_ln(
    const float* __restrict__ x, const int* __restrict__ xb,
    const float* __restrict__ wg, const float* __restrict__ cexp,
    const float* __restrict__ gamma, const float* __restrict__ beta,
    unsigned short* __restrict__ ebf) {
    __shared__ float sx[256];
    __shared__ float sg[4];
    __shared__ float rs[4], rq[4];
    int n = blockIdx.x, h = threadIdx.x;
    float xv = x[n * 256 + h];
    sx[h] = xv;
    __syncthreads();
    int xbn = xb[n];
    float eo;
    if (xbn == 0) {
        eo = beta[h] + xv;
    } else {
        int t = xbn - 1;
        int wv = h >> 6, lane = h & 63;
        float p = 0.f;
        const float* wgt = wg + t * 1024;
#pragma unroll
        for (int i = 0; i < 4; ++i) {
            int d = lane * 4 + i;
            p += sx[d] * wgt[d * 4 + wv];
        }
#pragma unroll
        for (int off = 32; off; off >>= 1) p += __shfl_down(p, off);
        if (lane == 0) sg[wv] = p;
        __syncthreads();
        float g0 = sg[0], g1 = sg[1], g2 = sg[2], g3 = sg[3];
        float mx = fmaxf(fmaxf(g0, g1), fmaxf(g2, g3));
        float e0 = __expf(g0 - mx), e1 = __expf(g1 - mx);
        float e2 = __expf(g2 - mx), e3 = __expf(g3 - mx);
        float inv = 1.f / (e0 + e1 + e2 + e3);
        const float* cr = cexp + (size_t)n * 2560;
        float o = (e0 * cr[h] + e1 * cr[256 + h] +
                   e2 * cr[512 + t * 512 + h] + e3 * cr[768 + t * 512 + h]) * inv;
        float s = o, q = o * o;
#pragma unroll
        for (int off = 32; off; off >>= 1) { s += __shfl_down(s, off); q += __shfl_down(q, off); }
        if (lane == 0) { rs[wv] = s; rq[wv] = q; }
        __syncthreads();
        float mu = (rs[0] + rs[1] + rs[2] + rs[3]) * (1.f / 256.f);
        float ex2 = (rq[0] + rq[1] + rq[2] + rq[3]) * (1.f / 256.f);
        float var = ex2 - mu * mu;
        eo = gamma[h] * (o - mu) * rsqrtf(var + LN_EPS) + beta[h] + xv;
    }
    ebf[n * 256 + h] = f2bf(eo);
}

// ---------------------------------------------------------------- vocab GEMM v9 (swapped MFMA, NT float4 stores)
// Grid 512 = 32 row-tiles x 2 col-splits x 8 col-groups (cg = bid&7 = XCD -> each XCD
// keeps one 3.2 MB emb slice resident in its L2). Block: 256 threads (4 waves),
// A tile (128x256) staged once into 64 KB LDS -> 2 blocks/CU, no barriers after stage.
// MFMA operands SWAPPED: acc = mfma(b, a, acc) so per lane: token = mf*16+l15,
// vocab cols = nf*16+kg*4+(0..3) -> float4 stores, 64 B contiguous per token per instr.
// PASS 1 stores are NONTEMPORAL float4: evict-first in L2 so the 823 MB prob stream
// doesn't displace the emb slice (round-6's NT failure was the scalar-4B pattern,
// not the NT bit; round-7's normal stores thrashed emb out of L2).
template <int PASS>
__global__ __launch_bounds__(256, 2) void vocab_pass(
    const unsigned short* __restrict__ ebf,
    const unsigned short* __restrict__ embbf,
    const float* __restrict__ vbias,
    float* __restrict__ psum,
    const float* __restrict__ denominv,
    float* __restrict__ prob) {
    __shared__ unsigned short sA[128 * 256];   // 64 KB

    int bid = blockIdx.x;
    int cg = bid & 7;             // XCD-pinned col group
    int cs = (bid >> 3) & 1;      // col split within the group
    int rt = bid >> 4;            // 32 row tiles
    int row0 = rt * 128;
    int tid = threadIdx.x;
    int wave = tid >> 6, lane = tid & 63;
    int l15 = lane & 15, kg = lane >> 4;      // kg in 0..3
    int wc = wave;

    // ---- stage A once (row-major [row][k], chunk slot s holds global chunk s^(row&7))
#pragma unroll
    for (int j = 0; j < 16; ++j) {
        int i = wave * 16 + j;
        int row = i * 2 + (lane >> 5);
        int slot = lane & 31;
        int kc = slot ^ (row & 7);
        const unsigned short* src = ebf + (size_t)(row0 + row) * 256 + kc * 8;
        __builtin_amdgcn_global_load_lds(
            (const __attribute__((address_space(1))) void*)src,
            (__attribute__((address_space(3))) void*)(sA + i * 512), 16, 0, 0);
    }
    asm volatile("s_waitcnt vmcnt(0)" ::: "memory");
    __syncthreads();

    float invd2[8];
    if (PASS == 1) {
#pragma unroll
        for (int mf = 0; mf < 8; ++mf)
            invd2[mf] = denominv[row0 + mf * 16 + l15];
    }
    float es2[8];
    if (PASS == 0) {
#pragma unroll
        for (int mf = 0; mf < 8; ++mf) es2[mf] = 0.f;
    }

    f32x4 zero4 = {0.f, 0.f, 0.f, 0.f};

    for (int ct = cg + 8 * cs; ct < NCT; ct += 16) {
        int mycol0 = ct * 256 + wc * 64;

        // B base pointers (per-lane rows of emb; layout matches frag directly)
        const unsigned short* bp[4];
        int c4[4]; f32x4 bv[4];
#pragma unroll
        for (int nf = 0; nf < 4; ++nf) {
            int gcol = mycol0 + nf * 16 + l15;
            int gcc = (gcol < VOC) ? gcol : (VOC - 1);
            bp[nf] = embbf + (size_t)gcc * 256;
            c4[nf] = mycol0 + nf * 16 + kg * 4;
            if (c4[nf] + 3 < VOC) {
                bv[nf] = *reinterpret_cast<const f32x4u*>(vbias + c4[nf]);
            } else {
#pragma unroll
                for (int r = 0; r < 4; ++r)
                    bv[nf][r] = (c4[nf] + r < VOC) ? vbias[c4[nf] + r] : -1e4f;
            }
        }

        f32x4 acc[8][4];
#pragma unroll
        for (int mf = 0; mf < 8; ++mf)
#pragma unroll
            for (int nf = 0; nf < 4; ++nf) acc[mf][nf] = zero4;

#pragma unroll
        for (int kstep = 0; kstep < 8; ++kstep) {
            bf16x8 b[4];
#pragma unroll
            for (int nf = 0; nf < 4; ++nf)
                b[nf] = *reinterpret_cast<const bf16x8*>(bp[nf] + kstep * 32 + kg * 8);
            bf16x8 a[8];
#pragma unroll
            for (int mf = 0; mf < 8; ++mf) {
                int row = mf * 16 + l15;
                int kc = kstep * 4 + kg;
                a[mf] = *reinterpret_cast<const bf16x8*>(
                    sA + row * 256 + ((kc ^ (row & 7)) * 8));
            }
            // swapped: first operand = b (vocab -> output rows), second = a (token -> output cols)
#pragma unroll
            for (int mf = 0; mf < 8; ++mf)
#pragma unroll
                for (int nf = 0; nf < 4; ++nf)
                    acc[mf][nf] = __builtin_amdgcn_mfma_f32_16x16x32_bf16(
                        b[nf], a[mf], acc[mf][nf], 0, 0, 0);
        }

        if (PASS == 0) {
#pragma unroll
            for (int mf = 0; mf < 8; ++mf) {
                float s = 0.f;
#pragma unroll
                for (int nf = 0; nf < 4; ++nf)
#pragma unroll
                    for (int r = 0; r < 4; ++r)
                        s += __expf(acc[mf][nf][r] + bv[nf][r]);
                es2[mf] += s;
            }
        } else {
#pragma unroll
            for (int mf = 0; mf < 8; ++mf) {
                float* pr = prob + (size_t)(row0 + mf * 16 + l15) * VOC;
#pragma unroll
                for (int nf = 0; nf < 4; ++nf) {
                    if (c4[nf] + 3 < VOC) {
                        f32x4 o;
#pragma unroll
                        for (int r = 0; r < 4; ++r)
                            o[r] = __expf(acc[mf][nf][r] + bv[nf][r]) * invd2[mf];
                        __builtin_nontemporal_store(
                            o, reinterpret_cast<f32x4u*>(pr + c4[nf]));
                    } else {
#pragma unroll
                        for (int r = 0; r < 4; ++r)
                            if (c4[nf] + r < VOC)
                                pr[c4[nf] + r] =
                                    __expf(acc[mf][nf][r] + bv[nf][r]) * invd2[mf];
                    }
                }
            }
        }
    }

    if (PASS == 0) {
        int slot = (cg * 2 + cs) * 4 + wc;    // 0..63
#pragma unroll
        for (int mf = 0; mf < 8; ++mf) {
            float v = es2[mf];
            v += __shfl_xor(v, 16);
            v += __shfl_xor(v, 32);
            if (kg == 0) {
                int row = row0 + mf * 16 + l15;
                psum[(size_t)slot * NTOK + row] = v;
            }
        }
    }
}

// ---------------------------------------------------------------- finalize: denom + inverse
__global__ __launch_bounds__(256) void finalize_denom(
    const float* __restrict__ psum, float* __restrict__ denom,
    float* __restrict__ denominv) {
    int row = blockIdx.x * 256 + threadIdx.x;
    float s = 0.f;
#pragma unroll
    for (int slot = 0; slot < 64; ++slot) s += psum[(size_t)slot * NTOK + row];
    denom[row] = s;
    denominv[row] = 1.f / s;
}

// ---------------------------------------------------------------- finalize: loss
__global__ __launch_bounds__(64) void finalize_loss(
    const float* __restrict__ denom,
    const unsigned short* __restrict__ ebf, const unsigned short* __restrict__ embbf,
    const float* __restrict__ vbias, const int* __restrict__ labels,
    float* __restrict__ loss) {
    int n = blockIdx.x, lane = threadIdx.x;
    int lf = labels[n];
    const unsigned short* ev = ebf + n * 256;
    const unsigned short* mv = embbf + (size_t)lf * 256;
    float p = 0.f;
#pragma unroll
    for (int i = 0; i < 4; ++i) p += bf2f(ev[lane * 4 + i]) * bf2f(mv[lane * 4 + i]);
#pragma unroll
    for (int off = 1; off < 64; off <<= 1) p += __shfl_xor(p, off);
    if (lane == 0) loss[n] = logf(denom[n]) - (p + vbias[lf]);
}

// ---------------------------------------------------------------- launch
extern "C" void kernel_launch(void* const* d_in, const int* in_sizes, int n_in,
                              void* d_out, int out_size, void* d_ws, size_t ws_size,
                              hipStream_t stream) {
    const float* x      = (const float*)d_in[0];
    const int*   labels = (const int*)d_in[1];
    const int*   xb     = (const int*)d_in[2];
    const float* Wsh    = (const float*)d_in[3];
    const float* bsh    = (const float*)d_in[4];
    const float* Wsp    = (const float*)d_in[5];
    const float* bsp    = (const float*)d_in[6];
    const float* wg     = (const float*)d_in[7];
    const float* vbias  = (const float*)d_in[8];
    const float* emb    = (const float*)d_in[9];
    const float* gamma  = (const float*)d_in[10];
    const float* beta   = (const float*)d_in[11];

    char* ws = (char*)d_ws;
    unsigned short* xbf   = (unsigned short*)(ws + 0);          // 2,097,152
    unsigned short* embbf = (unsigned short*)(ws + 2097152);    // 25,731,584
    unsigned short* Wtbf  = (unsigned short*)(ws + 27828736);   // 1,310,720
    float* cexp           = (float*)(ws + 29360128);            // 41,943,040
    unsigned short* ebf   = (unsigned short*)(ws + 71303168);   // 2,097,152
    float* psum           = (float*)(ws + 73400320);            // 1,048,576
    float* denom          = (float*)(ws + 74448896);            // 16,384
    float* denominv       = (float*)(ws + 74465280);            // 16,384

    float* prob = (float*)d_out;
    float* loss = prob + PROB_ELEMS;

    conv_f32_bf16<<<dim3(512), dim3(256), 0, stream>>>(x, xbf, NTOK * HID / 4);
    conv_f32_bf16<<<dim3(2048), dim3(256), 0, stream>>>(emb, embbf, VOC * HID / 4);
    wt_transpose<<<dim3(40, 4), dim3(256), 0, stream>>>(Wsh, Wsp, Wtbf);
    expert_gemm<<<dim3(64 * 20), dim3(256), 0, stream>>>(xbf, Wtbf, bsh, bsp, cexp);
    combine_ln<<<dim3(NTOK), dim3(256), 0, stream>>>(x, xb, wg, cexp, gamma, beta, ebf);
    vocab_pass<0><<<dim3(512), dim3(256), 0, stream>>>(ebf, embbf, vbias, psum, nullptr, nullptr);
    finalize_denom<<<dim3(16), dim3(256), 0, stream>>>(psum, denom, denominv);
    finalize_loss<<<dim3(NTOK), dim3(64), 0, stream>>>(denom, ebf, embbf, vbias, labels, loss);
    vocab_pass<1><<<dim3(512), dim3(256), 0, stream>>>(ebf, embbf, vbias, nullptr, denominv, prob);
}

// Round 9
// 1171.786 us; speedup vs baseline: 1.1910x; 1.1910x over previous
//
#include <hip/hip_runtime.h>

#define HID 256
#define VOC 50257
#define NCT128 393                // ceil(VOC / 128)
#define NTOK 4096
#define LN_EPS 1e-3f
#define PROB_ELEMS 205852672      // 4096 * 50257

typedef __attribute__((ext_vector_type(8))) short bf16x8;
typedef __attribute__((ext_vector_type(4))) float f32x4;
typedef __attribute__((ext_vector_type(4), aligned(4))) float f32x4u;  // 4B-aligned vector store

__device__ inline unsigned short f2bf(float f) {
    unsigned int u = __builtin_bit_cast(unsigned int, f);
    unsigned int r = u + 0x7FFFu + ((u >> 16) & 1u);
    return (unsigned short)(r >> 16);
}
__device__ inline float bf2f(unsigned short b) {
    unsigned int u = ((unsigned int)b) << 16;
    return __builtin_bit_cast(float, u);
}

// ---------------------------------------------------------------- conv f32->bf16
__global__ void conv_f32_bf16(const float* __restrict__ src,
                              unsigned short* __restrict__ dst, int n4) {
    int i = blockIdx.x * blockDim.x + threadIdx.x;
    int stride = gridDim.x * blockDim.x;
    for (; i < n4; i += stride) {
        float4 v = reinterpret_cast<const float4*>(src)[i];
        ushort4 o;
        o.x = f2bf(v.x); o.y = f2bf(v.y); o.z = f2bf(v.z); o.w = f2bf(v.w);
        reinterpret_cast<ushort4*>(dst)[i] = o;
    }
}

// ---------------------------------------------------------------- W transpose: W[e][k][h] f32 -> Wt[e*256+h][k] bf16
__global__ __launch_bounds__(256) void wt_transpose(
    const float* __restrict__ Wsh, const float* __restrict__ Wsp,
    unsigned short* __restrict__ Wtbf) {
    __shared__ float t[64][65];
    int gcol0 = blockIdx.x * 64;
    int k0 = blockIdx.y * 64;
    int e = gcol0 >> 8, h0 = gcol0 & 255;
    const float* Wp = (e < 2) ? (Wsh + e * 65536) : (Wsp + (e - 2) * 65536);
    int tid = threadIdx.x;
#pragma unroll
    for (int i = 0; i < 16; ++i) {
        int id = tid + i * 256;
        int k = id >> 6, h = id & 63;
        t[k][h] = Wp[(k0 + k) * 256 + h0 + h];
    }
    __syncthreads();
#pragma unroll
    for (int i = 0; i < 4; ++i) {
        int id = tid + i * 256;
        int h = id >> 4, kq = id & 15;
        ushort4 o;
        o.x = f2bf(t[kq * 4 + 0][h]); o.y = f2bf(t[kq * 4 + 1][h]);
        o.z = f2bf(t[kq * 4 + 2][h]); o.w = f2bf(t[kq * 4 + 3][h]);
        *reinterpret_cast<ushort4*>(Wtbf + (size_t)(gcol0 + h) * 256 + k0 + kq * 4) = o;
    }
}

// ---------------------------------------------------------------- expert GEMM
__global__ __launch_bounds__(256) void expert_gemm(
    const unsigned short* __restrict__ xbf,
    const unsigned short* __restrict__ Wtbf,
    const float* __restrict__ bsh, const float* __restrict__ bsp,
    float* __restrict__ cexp) {
    __shared__ unsigned short sA[64 * 256];
    __shared__ unsigned short sB[128 * 256];
    int bid = blockIdx.x;
    int rt = bid & 63;
    int ct = bid >> 6;
    int row0 = rt * 64, col0 = ct * 128;
    int tid = threadIdx.x;

#pragma unroll
    for (int i = 0; i < 8; ++i) {
        int id = tid + i * 256;
        int r = id >> 5, c = id & 31;
        bf16x8 v = *reinterpret_cast<const bf16x8*>(xbf + (row0 + r) * 256 + c * 8);
        *reinterpret_cast<bf16x8*>(sA + r * 256 + ((c ^ (r & 7)) * 8)) = v;
    }
#pragma unroll
    for (int i = 0; i < 16; ++i) {
        int id = tid + i * 256;
        int j = id >> 5, c = id & 31;
        bf16x8 v = *reinterpret_cast<const bf16x8*>(Wtbf + (size_t)(col0 + j) * 256 + c * 8);
        *reinterpret_cast<bf16x8*>(sB + j * 256 + ((c ^ (j & 7)) * 8)) = v;
    }
    __syncthreads();

    int lane = tid & 63, wave = tid >> 6;
    int wcol = wave * 32;
    int lrow = lane & 15, g = lane >> 4;
    f32x4 zero4 = {0.f, 0.f, 0.f, 0.f};
    f32x4 acc[4][2];
#pragma unroll
    for (int mf = 0; mf < 4; ++mf)
#pragma unroll
        for (int nf = 0; nf < 2; ++nf) acc[mf][nf] = zero4;

#pragma unroll
    for (int ks = 0; ks < 8; ++ks) {
        int kc = ks * 4 + g;
        bf16x8 a[4], b[2];
#pragma unroll
        for (int mf = 0; mf < 4; ++mf) {
            int r = mf * 16 + lrow;
            a[mf] = *reinterpret_cast<const bf16x8*>(sA + r * 256 + ((kc ^ (r & 7)) * 8));
        }
#pragma unroll
        for (int nf = 0; nf < 2; ++nf) {
            int j = wcol + nf * 16 + lrow;
            b[nf] = *reinterpret_cast<const bf16x8*>(sB + j * 256 + ((kc ^ (j & 7)) * 8));
        }
#pragma unroll
        for (int mf = 0; mf < 4; ++mf)
#pragma unroll
            for (int nf = 0; nf < 2; ++nf)
                acc[mf][nf] = __builtin_amdgcn_mfma_f32_16x16x32_bf16(a[mf], b[nf], acc[mf][nf], 0, 0, 0);
    }

#pragma unroll
    for (int nf = 0; nf < 2; ++nf) {
        int col = col0 + wcol + nf * 16 + lrow;
        int e = col >> 8, h = col & 255;
        float bias = (e < 2) ? bsh[e * 256 + h] : bsp[(e - 2) * 256 + h];
#pragma unroll
        for (int mf = 0; mf < 4; ++mf)
#pragma unroll
            for (int r = 0; r < 4; ++r) {
                int row = row0 + mf * 16 + g * 4 + r;
                cexp[(size_t)row * 2560 + col] = acc[mf][nf][r] + bias;
            }
    }
}

// ---------------------------------------------------------------- gates + combine + LN + residual
__global__ __launch_bounds__(256) void combine_ln(
    const float* __restrict__ x, const int* __restrict__ xb,
    const float* __restrict__ wg, const float* __restrict__ cexp,
    const float* __restrict__ gamma, const float* __restrict__ beta,
    unsigned short* __restrict__ ebf) {
    __shared__ float sx[256];
    __shared__ float sg[4];
    __shared__ float rs[4], rq[4];
    int n = blockIdx.x, h = threadIdx.x;
    float xv = x[n * 256 + h];
    sx[h] = xv;
    __syncthreads();
    int xbn = xb[n];
    float eo;
    if (xbn == 0) {
        eo = beta[h] + xv;
    } else {
        int t = xbn - 1;
        int wv = h >> 6, lane = h & 63;
        float p = 0.f;
        const float* wgt = wg + t * 1024;
#pragma unroll
        for (int i = 0; i < 4; ++i) {
            int d = lane * 4 + i;
            p += sx[d] * wgt[d * 4 + wv];
        }
#pragma unroll
        for (int off = 32; off; off >>= 1) p += __shfl_down(p, off);
        if (lane == 0) sg[wv] = p;
        __syncthreads();
        float g0 = sg[0], g1 = sg[1], g2 = sg[2], g3 = sg[3];
        float mx = fmaxf(fmaxf(g0, g1), fmaxf(g2, g3));
        float e0 = __expf(g0 - mx), e1 = __expf(g1 - mx);
        float e2 = __expf(g2 - mx), e3 = __expf(g3 - mx);
        float inv = 1.f / (e0 + e1 + e2 + e3);
        const float* cr = cexp + (size_t)n * 2560;
        float o = (e0 * cr[h] + e1 * cr[256 + h] +
                   e2 * cr[512 + t * 512 + h] + e3 * cr[768 + t * 512 + h]) * inv;
        float s = o, q = o * o;
#pragma unroll
        for (int off = 32; off; off >>= 1) { s += __shfl_down(s, off); q += __shfl_down(q, off); }
        if (lane == 0) { rs[wv] = s; rq[wv] = q; }
        __syncthreads();
        float mu = (rs[0] + rs[1] + rs[2] + rs[3]) * (1.f / 256.f);
        float ex2 = (rq[0] + rq[1] + rq[2] + rq[3]) * (1.f / 256.f);
        float var = ex2 - mu * mu;
        eo = gamma[h] * (o - mu) * rsqrtf(var + LN_EPS) + beta[h] + xv;
    }
    ebf[n * 256 + h] = f2bf(eo);
}

// ---------------------------------------------------------------- vocab GEMM v10 (deferred stores)
// Grid 512 = 32 row-tiles x 2 col-splits x 8 col-groups (cg = bid&7 = XCD L2 pinning).
// Block: 256 threads (4 waves), A tile (128x256) staged once into 64 KB LDS ->
// 2 blocks/CU. Tile = 128 cols/iter (wave: 8 m-frags x 2 n-frags, swapped MFMA).
// KEY (vmcnt FIFO decoupling): all 16 b-loads of tile t are issued into registers
// (ball) BEFORE the stores of tile t-1 (pend) are issued. FIFO retires the loads
// first, so the MFMA wait never drains the store batch -- stores flow out during
// the compute phase. Stores are NORMAL f32x4 (NT refuted in r6/r8).
template <int PASS>
__global__ __launch_bounds__(256, 2) void vocab_pass(
    const unsigned short* __restrict__ ebf,
    const unsigned short* __restrict__ embbf,
    const float* __restrict__ vbias,
    float* __restrict__ psum,
    const float* __restrict__ denominv,
    float* __restrict__ prob) {
    __shared__ unsigned short sA[128 * 256];   // 64 KB

    int bid = blockIdx.x;
    int cg = bid & 7;             // XCD-pinned col group
    int cs = (bid >> 3) & 1;      // col split within the group
    int rt = bid >> 4;            // 32 row tiles
    int row0 = rt * 128;
    int tid = threadIdx.x;
    int wave = tid >> 6, lane = tid & 63;
    int l15 = lane & 15, kg = lane >> 4;      // kg in 0..3
    int wc = wave;

    // ---- stage A once (row-major [row][k], chunk slot s holds global chunk s^(row&7))
#pragma unroll
    for (int j = 0; j < 16; ++j) {
        int i = wave * 16 + j;
        int row = i * 2 + (lane >> 5);
        int slot = lane & 31;
        int kc = slot ^ (row & 7);
        const unsigned short* src = ebf + (size_t)(row0 + row) * 256 + kc * 8;
        __builtin_amdgcn_global_load_lds(
            (const __attribute__((address_space(1))) void*)src,
            (__attribute__((address_space(3))) void*)(sA + i * 512), 16, 0, 0);
    }
    asm volatile("s_waitcnt vmcnt(0)" ::: "memory");
    __syncthreads();

    float invd2[8];
    if (PASS == 1) {
#pragma unroll
        for (int mf = 0; mf < 8; ++mf)
            invd2[mf] = denominv[row0 + mf * 16 + l15];
    }
    float es2[8];
    if (PASS == 0) {
#pragma unroll
        for (int mf = 0; mf < 8; ++mf) es2[mf] = 0.f;
    }

    f32x4 zero4 = {0.f, 0.f, 0.f, 0.f};
    f32x4 pend[8][2];             // deferred prob values of previous tile (PASS 1)
    int c4p[2] = {0, 0};
    int it = 0;

    for (int ct = cg + 8 * cs; ct < NCT128; ct += 16, ++it) {
        int mycol0 = ct * 128 + wc * 32;

        // ---- column metadata + vbias (loads)
        const unsigned short* bp[2];
        int c4[2]; f32x4 bv[2];
#pragma unroll
        for (int nf = 0; nf < 2; ++nf) {
            int gcol = mycol0 + nf * 16 + l15;
            int gcc = (gcol < VOC) ? gcol : (VOC - 1);
            bp[nf] = embbf + (size_t)gcc * 256;
            c4[nf] = mycol0 + nf * 16 + kg * 4;
            if (c4[nf] + 3 < VOC) {
                bv[nf] = *reinterpret_cast<const f32x4u*>(vbias + c4[nf]);
            } else {
#pragma unroll
                for (int r = 0; r < 4; ++r)
                    bv[nf][r] = (c4[nf] + r < VOC) ? vbias[c4[nf] + r] : -1e4f;
            }
        }

        // ---- issue ALL b-loads for this tile FIRST (before any stores)
        bf16x8 ball[2][8];
#pragma unroll
        for (int ks = 0; ks < 8; ++ks)
#pragma unroll
            for (int nf = 0; nf < 2; ++nf)
                ball[nf][ks] = *reinterpret_cast<const bf16x8*>(bp[nf] + ks * 32 + kg * 8);

        // ---- deferred stores of previous tile (issued AFTER this tile's loads)
        if (PASS == 1 && it > 0) {
#pragma unroll
            for (int mf = 0; mf < 8; ++mf) {
                float* pr = prob + (size_t)(row0 + mf * 16 + l15) * VOC;
#pragma unroll
                for (int nf = 0; nf < 2; ++nf) {
                    if (c4p[nf] + 3 < VOC) {
                        *reinterpret_cast<f32x4u*>(pr + c4p[nf]) = pend[mf][nf];
                    } else {
#pragma unroll
                        for (int r = 0; r < 4; ++r)
                            if (c4p[nf] + r < VOC) pr[c4p[nf] + r] = pend[mf][nf][r];
                    }
                }
            }
        }

        // ---- MFMA (waits retire the b-loads; stores are newer in FIFO, keep draining)
        f32x4 acc[8][2];
#pragma unroll
        for (int mf = 0; mf < 8; ++mf)
#pragma unroll
            for (int nf = 0; nf < 2; ++nf) acc[mf][nf] = zero4;

#pragma unroll
        for (int ks = 0; ks < 8; ++ks) {
            bf16x8 a[8];
#pragma unroll
            for (int mf = 0; mf < 8; ++mf) {
                int row = mf * 16 + l15;
                int kc = ks * 4 + kg;
                a[mf] = *reinterpret_cast<const bf16x8*>(
                    sA + row * 256 + ((kc ^ (row & 7)) * 8));
            }
#pragma unroll
            for (int mf = 0; mf < 8; ++mf)
#pragma unroll
                for (int nf = 0; nf < 2; ++nf)
                    acc[mf][nf] = __builtin_amdgcn_mfma_f32_16x16x32_bf16(
                        ball[nf][ks], a[mf], acc[mf][nf], 0, 0, 0);
        }

        // ---- epilogue
        if (PASS == 0) {
#pragma unroll
            for (int mf = 0; mf < 8; ++mf) {
                float s = 0.f;
#pragma unroll
                for (int nf = 0; nf < 2; ++nf)
#pragma unroll
                    for (int r = 0; r < 4; ++r)
                        s += __expf(acc[mf][nf][r] + bv[nf][r]);
                es2[mf] += s;
            }
        } else {
#pragma unroll
            for (int mf = 0; mf < 8; ++mf)
#pragma unroll
                for (int nf = 0; nf < 2; ++nf)
#pragma unroll
                    for (int r = 0; r < 4; ++r)
                        pend[mf][nf][r] = __expf(acc[mf][nf][r] + bv[nf][r]) * invd2[mf];
            c4p[0] = c4[0]; c4p[1] = c4[1];
        }
    }

    if (PASS == 1) {
        // flush last tile
        if (it > 0) {
#pragma unroll
            for (int mf = 0; mf < 8; ++mf) {
                float* pr = prob + (size_t)(row0 + mf * 16 + l15) * VOC;
#pragma unroll
                for (int nf = 0; nf < 2; ++nf) {
                    if (c4p[nf] + 3 < VOC) {
                        *reinterpret_cast<f32x4u*>(pr + c4p[nf]) = pend[mf][nf];
                    } else {
#pragma unroll
                        for (int r = 0; r < 4; ++r)
                            if (c4p[nf] + r < VOC) pr[c4p[nf] + r] = pend[mf][nf][r];
                    }
                }
            }
        }
    } else {
        int slot = (cg * 2 + cs) * 4 + wc;    // 0..63
#pragma unroll
        for (int mf = 0; mf < 8; ++mf) {
            float v = es2[mf];
            v += __shfl_xor(v, 16);
            v += __shfl_xor(v, 32);
            if (kg == 0) {
                int row = row0 + mf * 16 + l15;
                psum[(size_t)slot * NTOK + row] = v;
            }
        }
    }
}

// ---------------------------------------------------------------- finalize: denom + inverse
__global__ __launch_bounds__(256) void finalize_denom(
    const float* __restrict__ psum, float* __restrict__ denom,
    float* __restrict__ denominv) {
    int row = blockIdx.x * 256 + threadIdx.x;
    float s = 0.f;
#pragma unroll
    for (int slot = 0; slot < 64; ++slot) s += psum[(size_t)slot * NTOK + row];
    denom[row] = s;
    denominv[row] = 1.f / s;
}

// ---------------------------------------------------------------- finalize: loss
__global__ __launch_bounds__(64) void finalize_loss(
    const float* __restrict__ denom,
    const unsigned short* __restrict__ ebf, const unsigned short* __restrict__ embbf,
    const float* __restrict__ vbias, const int* __restrict__ labels,
    float* __restrict__ loss) {
    int n = blockIdx.x, lane = threadIdx.x;
    int lf = labels[n];
    const unsigned short* ev = ebf + n * 256;
    const unsigned short* mv = embbf + (size_t)lf * 256;
    float p = 0.f;
#pragma unroll
    for (int i = 0; i < 4; ++i) p += bf2f(ev[lane * 4 + i]) * bf2f(mv[lane * 4 + i]);
#pragma unroll
    for (int off = 1; off < 64; off <<= 1) p += __shfl_xor(p, off);
    if (lane == 0) loss[n] = logf(denom[n]) - (p + vbias[lf]);
}

// ---------------------------------------------------------------- launch
extern "C" void kernel_launch(void* const* d_in, const int* in_sizes, int n_in,
                              void* d_out, int out_size, void* d_ws, size_t ws_size,
                              hipStream_t stream) {
    const float* x      = (const float*)d_in[0];
    const int*   labels = (const int*)d_in[1];
    const int*   xb     = (const int*)d_in[2];
    const float* Wsh    = (const float*)d_in[3];
    const float* bsh    = (const float*)d_in[4];
    const float* Wsp    = (const float*)d_in[5];
    const float* bsp    = (const float*)d_in[6];
    const float* wg     = (const float*)d_in[7];
    const float* vbias  = (const float*)d_in[8];
    const float* emb    = (const float*)d_in[9];
    const float* gamma  = (const float*)d_in[10];
    const float* beta   = (const float*)d_in[11];

    char* ws = (char*)d_ws;
    unsigned short* xbf   = (unsigned short*)(ws + 0);          // 2,097,152
    unsigned short* embbf = (unsigned short*)(ws + 2097152);    // 25,731,584
    unsigned short* Wtbf  = (unsigned short*)(ws + 27828736);   // 1,310,720
    float* cexp           = (float*)(ws + 29360128);            // 41,943,040
    unsigned short* ebf   = (unsigned short*)(ws + 71303168);   // 2,097,152
    float* psum           = (float*)(ws + 73400320);            // 1,048,576
    float* denom          = (float*)(ws + 74448896);            // 16,384
    float* denominv       = (float*)(ws + 74465280);            // 16,384

    float* prob = (float*)d_out;
    float* loss = prob + PROB_ELEMS;

    conv_f32_bf16<<<dim3(512), dim3(256), 0, stream>>>(x, xbf, NTOK * HID / 4);
    conv_f32_bf16<<<dim3(2048), dim3(256), 0, stream>>>(emb, embbf, VOC * HID / 4);
    wt_transpose<<<dim3(40, 4), dim3(256), 0, stream>>>(Wsh, Wsp, Wtbf);
    expert_gemm<<<dim3(64 * 20), dim3(256), 0, stream>>>(xbf, Wtbf, bsh, bsp, cexp);
    combine_ln<<<dim3(NTOK), dim3(256), 0, stream>>>(x, xb, wg, cexp, gamma, beta, ebf);
    vocab_pass<0><<<dim3(512), dim3(256), 0, stream>>>(ebf, embbf, vbias, psum, nullptr, nullptr);
    finalize_denom<<<dim3(16), dim3(256), 0, stream>>>(psum, denom, denominv);
    finalize_loss<<<dim3(NTOK), dim3(64), 0, stream>>>(denom, ebf, embbf, vbias, labels, loss);
    vocab_pass<1><<<dim3(512), dim3(256), 0, stream>>>(ebf, embbf, vbias, nullptr, denominv, prob);
}

// Round 10
// 540.117 us; speedup vs baseline: 2.5838x; 2.1695x over previous
//
#include <hip/hip_runtime.h>

#define HID 256
#define VOC 50257
#define NTOK 4096
#define NCT3 393                  // ceil(VOC / 128)
#define CG 8                      // column groups (== XCDs)
#define TN 128                    // cols per iteration
#define LN_EPS 1e-3f
#define PROB_ELEMS 205852672      // 4096 * 50257

typedef __attribute__((ext_vector_type(8))) short bf16x8;
typedef __attribute__((ext_vector_type(4))) float f32x4;
typedef __attribute__((ext_vector_type(16))) float f32x16;

__device__ inline unsigned short f2bf(float f) {
    unsigned int u = __builtin_bit_cast(unsigned int, f);
    unsigned int r = u + 0x7FFFu + ((u >> 16) & 1u);
    return (unsigned short)(r >> 16);
}
__device__ inline float bf2f(unsigned short b) {
    unsigned int u = ((unsigned int)b) << 16;
    return __builtin_bit_cast(float, u);
}

// ---------------------------------------------------------------- conv f32->bf16
__global__ void conv_f32_bf16(const float* __restrict__ src,
                              unsigned short* __restrict__ dst, int n4) {
    int i = blockIdx.x * blockDim.x + threadIdx.x;
    int stride = gridDim.x * blockDim.x;
    for (; i < n4; i += stride) {
        float4 v = reinterpret_cast<const float4*>(src)[i];
        ushort4 o;
        o.x = f2bf(v.x); o.y = f2bf(v.y); o.z = f2bf(v.z); o.w = f2bf(v.w);
        reinterpret_cast<ushort4*>(dst)[i] = o;
    }
}

// ---------------------------------------------------------------- W transpose: W[e][k][h] f32 -> Wt[e*256+h][k] bf16
__global__ __launch_bounds__(256) void wt_transpose(
    const float* __restrict__ Wsh, const float* __restrict__ Wsp,
    unsigned short* __restrict__ Wtbf) {
    __shared__ float t[64][65];
    int gcol0 = blockIdx.x * 64;
    int k0 = blockIdx.y * 64;
    int e = gcol0 >> 8, h0 = gcol0 & 255;
    const float* Wp = (e < 2) ? (Wsh + e * 65536) : (Wsp + (e - 2) * 65536);
    int tid = threadIdx.x;
#pragma unroll
    for (int i = 0; i < 16; ++i) {
        int id = tid + i * 256;
        int k = id >> 6, h = id & 63;
        t[k][h] = Wp[(k0 + k) * 256 + h0 + h];
    }
    __syncthreads();
#pragma unroll
    for (int i = 0; i < 4; ++i) {
        int id = tid + i * 256;
        int h = id >> 4, kq = id & 15;
        ushort4 o;
        o.x = f2bf(t[kq * 4 + 0][h]); o.y = f2bf(t[kq * 4 + 1][h]);
        o.z = f2bf(t[kq * 4 + 2][h]); o.w = f2bf(t[kq * 4 + 3][h]);
        *reinterpret_cast<ushort4*>(Wtbf + (size_t)(gcol0 + h) * 256 + k0 + kq * 4) = o;
    }
}

// ---------------------------------------------------------------- expert GEMM
__global__ __launch_bounds__(256) void expert_gemm(
    const unsigned short* __restrict__ xbf,
    const unsigned short* __restrict__ Wtbf,
    const float* __restrict__ bsh, const float* __restrict__ bsp,
    float* __restrict__ cexp) {
    __shared__ unsigned short sA[64 * 256];
    __shared__ unsigned short sB[128 * 256];
    int bid = blockIdx.x;
    int rt = bid & 63;
    int ct = bid >> 6;
    int row0 = rt * 64, col0 = ct * 128;
    int tid = threadIdx.x;

#pragma unroll
    for (int i = 0; i < 8; ++i) {
        int id = tid + i * 256;
        int r = id >> 5, c = id & 31;
        bf16x8 v = *reinterpret_cast<const bf16x8*>(xbf + (row0 + r) * 256 + c * 8);
        *reinterpret_cast<bf16x8*>(sA + r * 256 + ((c ^ (r & 7)) * 8)) = v;
    }
#pragma unroll
    for (int i = 0; i < 16; ++i) {
        int id = tid + i * 256;
        int j = id >> 5, c = id & 31;
        bf16x8 v = *reinterpret_cast<const bf16x8*>(Wtbf + (size_t)(col0 + j) * 256 + c * 8);
        *reinterpret_cast<bf16x8*>(sB + j * 256 + ((c ^ (j & 7)) * 8)) = v;
    }
    __syncthreads();

    int lane = tid & 63, wave = tid >> 6;
    int wcol = wave * 32;
    int lrow = lane & 15, g = lane >> 4;
    f32x4 zero4 = {0.f, 0.f, 0.f, 0.f};
    f32x4 acc[4][2];
#pragma unroll
    for (int mf = 0; mf < 4; ++mf)
#pragma unroll
        for (int nf = 0; nf < 2; ++nf) acc[mf][nf] = zero4;

#pragma unroll
    for (int ks = 0; ks < 8; ++ks) {
        int kc = ks * 4 + g;
        bf16x8 a[4], b[2];
#pragma unroll
        for (int mf = 0; mf < 4; ++mf) {
            int r = mf * 16 + lrow;
            a[mf] = *reinterpret_cast<const bf16x8*>(sA + r * 256 + ((kc ^ (r & 7)) * 8));
        }
#pragma unroll
        for (int nf = 0; nf < 2; ++nf) {
            int j = wcol + nf * 16 + lrow;
            b[nf] = *reinterpret_cast<const bf16x8*>(sB + j * 256 + ((kc ^ (j & 7)) * 8));
        }
#pragma unroll
        for (int mf = 0; mf < 4; ++mf)
#pragma unroll
            for (int nf = 0; nf < 2; ++nf)
                acc[mf][nf] = __builtin_amdgcn_mfma_f32_16x16x32_bf16(a[mf], b[nf], acc[mf][nf], 0, 0, 0);
    }

#pragma unroll
    for (int nf = 0; nf < 2; ++nf) {
        int col = col0 + wcol + nf * 16 + lrow;
        int e = col >> 8, h = col & 255;
        float bias = (e < 2) ? bsh[e * 256 + h] : bsp[(e - 2) * 256 + h];
#pragma unroll
        for (int mf = 0; mf < 4; ++mf)
#pragma unroll
            for (int r = 0; r < 4; ++r) {
                int row = row0 + mf * 16 + g * 4 + r;
                cexp[(size_t)row * 2560 + col] = acc[mf][nf][r] + bias;
            }
    }
}

// ---------------------------------------------------------------- gates + combine + LN + residual
__global__ __launch_bounds__(256) void combine_ln(
    const float* __restrict__ x, const int* __restrict__ xb,
    const float* __restrict__ wg, const float* __restrict__ cexp,
    const float* __restrict__ gamma, const float* __restrict__ beta,
    unsigned short* __restrict__ ebf) {
    __shared__ float sx[256];
    __shared__ float sg[4];
    __shared__ float rs[4], rq[4];
    int n = blockIdx.x, h = threadIdx.x;
    float xv = x[n * 256 + h];
    sx[h] = xv;
    __syncthreads();
    int xbn = xb[n];
    float eo;
    if (xbn == 0) {
        eo = beta[h] + xv;
    } else {
        int t = xbn - 1;
        int wv = h >> 6, lane = h & 63;
        float p = 0.f;
        const float* wgt = wg + t * 1024;
#pragma unroll
        for (int i = 0; i < 4; ++i) {
            int d = lane * 4 + i;
            p += sx[d] * wgt[d * 4 + wv];
        }
#pragma unroll
        for (int off = 32; off; off >>= 1) p += __shfl_down(p, off);
        if (lane == 0) sg[wv] = p;
        __syncthreads();
        float g0 = sg[0], g1 = sg[1], g2 = sg[2], g3 = sg[3];
        float mx = fmaxf(fmaxf(g0, g1), fmaxf(g2, g3));
        float e0 = __expf(g0 - mx), e1 = __expf(g1 - mx);
        float e2 = __expf(g2 - mx), e3 = __expf(g3 - mx);
        float inv = 1.f / (e0 + e1 + e2 + e3);
        const float* cr = cexp + (size_t)n * 2560;
        float o = (e0 * cr[h] + e1 * cr[256 + h] +
                   e2 * cr[512 + t * 512 + h] + e3 * cr[768 + t * 512 + h]) * inv;
        float s = o, q = o * o;
#pragma unroll
        for (int off = 32; off; off >>= 1) { s += __shfl_down(s, off); q += __shfl_down(q, off); }
        if (lane == 0) { rs[wv] = s; rq[wv] = q; }
        __syncthreads();
        float mu = (rs[0] + rs[1] + rs[2] + rs[3]) * (1.f / 256.f);
        float ex2 = (rq[0] + rq[1] + rq[2] + rq[3]) * (1.f / 256.f);
        float var = ex2 - mu * mu;
        eo = gamma[h] * (o - mu) * rsqrtf(var + LN_EPS) + beta[h] + xv;
    }
    ebf[n * 256 + h] = f2bf(eo);
}

// ---------------------------------------------------------------- vocab GEMM v3 (round-3 best: 543 us total)
// Persistent: 32 row-tiles x 8 col-groups = 256 blocks, 512 threads (8 waves).
// A (128 rows x 256 K) in REGISTERS per wave; B streamed through LDS dbuf.
// Stage next tile FIRST, compute current, vmcnt(0)+barrier, epilogue after the
// barrier so prob stores drain under the NEXT iteration's stage+compute.
template <int PASS>
__global__ __launch_bounds__(512, 2) void big_gemm(
    const unsigned short* __restrict__ ebf,
    const unsigned short* __restrict__ embbf,
    const float* __restrict__ vbias,
    float* __restrict__ psum,
    const float* __restrict__ denom,
    float* __restrict__ prob) {
    __shared__ unsigned short sB[2][TN * 256];   // 128 KB

    int bid = blockIdx.x;
    int rt = bid >> 3;           // 32 row tiles
    int cg = bid & 7;            // col group == XCD
    int row0 = rt * 128;
    int tid = threadIdx.x;
    int wave = tid >> 6, lane = tid & 63;
    int l31 = lane & 31, hi = lane >> 5;
    int wr = wave >> 2, wc = wave & 3;
    int nmy = (NCT3 - cg + CG - 1) / CG;   // tiles ct = cg, cg+8, ...

    // ---- A into registers: a[mf][ks], row = row0 + wr*64 + mf*32 + l31,
    //      k = ks*16 + hi*8 + i
    bf16x8 a[2][16];
    {
        const unsigned short* ab =
            ebf + (size_t)(row0 + wr * 64 + l31) * 256 + hi * 8;
#pragma unroll
        for (int mf = 0; mf < 2; ++mf)
#pragma unroll
            for (int ks = 0; ks < 16; ++ks)
                a[mf][ks] = *reinterpret_cast<const bf16x8*>(ab + mf * 32 * 256 + ks * 16);
    }

    // ---- stage helper: LDS layout col-major [col][256k], 16B chunk swizzle ^ (col&7)
    auto stage = [&](int ct, int buf) {
        int col0 = ct * TN;
#pragma unroll
        for (int i = 0; i < 8; ++i) {
            int col = i * 16 + wave * 2 + hi;               // per-lane (for src only)
            int gcol = col0 + col; if (gcol >= VOC) gcol = VOC - 1;
            const unsigned short* src =
                embbf + (size_t)gcol * 256 + ((l31 ^ (col & 7)) * 8);
            // wave-uniform LDS base; lanes write base + lane*16
            unsigned short* dst = (unsigned short*)sB[buf] + (size_t)(i * 512 + wave * 64) * 8;
            __builtin_amdgcn_global_load_lds(
                (const __attribute__((address_space(1))) void*)src,
                (__attribute__((address_space(3))) void*)dst, 16, 0, 0);
        }
    };

    stage(cg, 0);
    asm volatile("s_waitcnt vmcnt(0)" ::: "memory");
    __syncthreads();

    float invd[2][16];
    if (PASS == 1) {
#pragma unroll
        for (int mf = 0; mf < 2; ++mf)
#pragma unroll
            for (int r = 0; r < 16; ++r) {
                int row = row0 + wr * 64 + mf * 32 + (r & 3) + 8 * (r >> 2) + 4 * hi;
                invd[mf][r] = 1.f / denom[row];
            }
    }
    float es[2][16];
    if (PASS == 0) {
#pragma unroll
        for (int mf = 0; mf < 2; ++mf)
#pragma unroll
            for (int r = 0; r < 16; ++r) es[mf][r] = 0.f;
    }

    f32x16 zz = {0.f,0.f,0.f,0.f,0.f,0.f,0.f,0.f,0.f,0.f,0.f,0.f,0.f,0.f,0.f,0.f};

    for (int it = 0; it < nmy; ++it) {
        int ct = cg + it * CG;
        if (it + 1 < nmy) stage(ct + CG, (it + 1) & 1);

        int gc = ct * TN + wc * 32 + l31;
        float bvb;
        if (PASS == 0) bvb = (gc < VOC) ? vbias[gc] : -1e4f;
        else           bvb = vbias[(gc < VOC) ? gc : (VOC - 1)];

        const unsigned short* sBc = (const unsigned short*)sB[it & 1];
        int bcol = wc * 32 + l31;
        f32x16 c0 = zz, c1 = zz;
#pragma unroll
        for (int ks = 0; ks < 16; ++ks) {
            int kc = ks * 2 + hi;
            bf16x8 b = *reinterpret_cast<const bf16x8*>(
                sBc + bcol * 256 + ((kc ^ (bcol & 7)) * 8));
            c0 = __builtin_amdgcn_mfma_f32_32x32x16_bf16(a[0][ks], b, c0, 0, 0, 0);
            c1 = __builtin_amdgcn_mfma_f32_32x32x16_bf16(a[1][ks], b, c1, 0, 0, 0);
        }

        asm volatile("s_waitcnt vmcnt(0)" ::: "memory");
        __syncthreads();

        // epilogue after barrier: overlaps with next iteration's staging/compute
        if (PASS == 0) {
#pragma unroll
            for (int r = 0; r < 16; ++r) {
                es[0][r] += __expf(c0[r] + bvb);
                es[1][r] += __expf(c1[r] + bvb);
            }
        } else {
            if (gc < VOC) {
#pragma unroll
                for (int r = 0; r < 16; ++r) {
                    int rowr = row0 + wr * 64 + (r & 3) + 8 * (r >> 2) + 4 * hi;
                    prob[(size_t)rowr * VOC + gc] = __expf(c0[r] + bvb) * invd[0][r];
                    prob[(size_t)(rowr + 32) * VOC + gc] = __expf(c1[r] + bvb) * invd[1][r];
                }
            }
        }
    }

    if (PASS == 0) {
        // reduce over the 32 cols (l31) per row; lanes l31==0 write
#pragma unroll
        for (int mf = 0; mf < 2; ++mf)
#pragma unroll
            for (int r = 0; r < 16; ++r) {
                float v = es[mf][r];
#pragma unroll
                for (int off = 1; off < 32; off <<= 1) v += __shfl_xor(v, off);
                if (l31 == 0) {
                    int row = row0 + wr * 64 + mf * 32 + (r & 3) + 8 * (r >> 2) + 4 * hi;
                    psum[(size_t)row * 32 + cg * 4 + wc] = v;
                }
            }
    }
}

// ---------------------------------------------------------------- finalize: denom + loss
__global__ __launch_bounds__(64) void finalize_k(
    const float* __restrict__ psum,
    const unsigned short* __restrict__ ebf, const unsigned short* __restrict__ embbf,
    const float* __restrict__ vbias, const int* __restrict__ labels,
    float* __restrict__ denom, float* __restrict__ loss) {
    int n = blockIdx.x, lane = threadIdx.x;
    float s = (lane < 32) ? psum[(size_t)n * 32 + lane] : 0.f;
#pragma unroll
    for (int off = 1; off < 32; off <<= 1) s += __shfl_xor(s, off);
    int lf = labels[n];
    const unsigned short* ev = ebf + n * 256;
    const unsigned short* mv = embbf + (size_t)lf * 256;
    float p = 0.f;
#pragma unroll
    for (int i = 0; i < 4; ++i) p += bf2f(ev[lane * 4 + i]) * bf2f(mv[lane * 4 + i]);
#pragma unroll
    for (int off = 1; off < 64; off <<= 1) p += __shfl_xor(p, off);
    if (lane == 0) {
        denom[n] = s;
        loss[n] = logf(s) - (p + vbias[lf]);
    }
}

// ---------------------------------------------------------------- launch
extern "C" void kernel_launch(void* const* d_in, const int* in_sizes, int n_in,
                              void* d_out, int out_size, void* d_ws, size_t ws_size,
                              hipStream_t stream) {
    const float* x      = (const float*)d_in[0];
    const int*   labels = (const int*)d_in[1];
    const int*   xb     = (const int*)d_in[2];
    const float* Wsh    = (const float*)d_in[3];
    const float* bsh    = (const float*)d_in[4];
    const float* Wsp    = (const float*)d_in[5];
    const float* bsp    = (const float*)d_in[6];
    const float* wg     = (const float*)d_in[7];
    const float* vbias  = (const float*)d_in[8];
    const float* emb    = (const float*)d_in[9];
    const float* gamma  = (const float*)d_in[10];
    const float* beta   = (const float*)d_in[11];

    char* ws = (char*)d_ws;
    unsigned short* xbf   = (unsigned short*)(ws + 0);          // 2,097,152
    unsigned short* embbf = (unsigned short*)(ws + 2097152);    // 25,731,584
    unsigned short* Wtbf  = (unsigned short*)(ws + 27828736);   // 1,310,720
    float* cexp           = (float*)(ws + 29360128);            // 41,943,040
    unsigned short* ebf   = (unsigned short*)(ws + 71303168);   // 2,097,152
    float* psum           = (float*)(ws + 73400320);            // 524,288
    float* denom          = (float*)(ws + 73924608);            // 16,384

    float* prob = (float*)d_out;
    float* loss = prob + PROB_ELEMS;

    conv_f32_bf16<<<dim3(512), dim3(256), 0, stream>>>(x, xbf, NTOK * HID / 4);
    conv_f32_bf16<<<dim3(2048), dim3(256), 0, stream>>>(emb, embbf, VOC * HID / 4);
    wt_transpose<<<dim3(40, 4), dim3(256), 0, stream>>>(Wsh, Wsp, Wtbf);
    expert_gemm<<<dim3(64 * 20), dim3(256), 0, stream>>>(xbf, Wtbf, bsh, bsp, cexp);
    combine_ln<<<dim3(NTOK), dim3(256), 0, stream>>>(x, xb, wg, cexp, gamma, beta, ebf);
    big_gemm<0><<<dim3(256), dim3(512), 0, stream>>>(ebf, embbf, vbias, psum, nullptr, nullptr);
    finalize_k<<<dim3(NTOK), dim3(64), 0, stream>>>(psum, ebf, embbf, vbias, labels, denom, loss);
    big_gemm<1><<<dim3(256), dim3(512), 0, stream>>>(ebf, embbf, vbias, nullptr, denom, prob);
}